// Round 8
// baseline (309.172 us; speedup 1.0000x reference)
//
#include <hip/hip_runtime.h>
#include <math.h>

#define NEG_SLOPE 0.2f

// fp32 -> bf16 round-to-nearest-even
__device__ __forceinline__ unsigned f2bf(float f) {
    unsigned u = __float_as_uint(f);
    return (u + 0x7fffu + ((u >> 16) & 1u)) >> 16;
}

// ============================================================
// count_rank over REAL edges only (self-loops take the last
// slot of each segment deterministically — no atomic needed).
// 4 VGPR, no LDS -> high occupancy for the latency-bound atomics.
// ============================================================
__global__ __launch_bounds__(256) void count_rank_k(
    const int* __restrict__ ei, int* __restrict__ deg, int* __restrict__ rank,
    int E)
{
    int e = blockIdx.x * 256 + threadIdx.x;
    if (e >= E) return;
    int d = ei[E + e];
    rank[e] = atomicAdd(&deg[d], 1);   // coalesced rank store, no downstream dep
}

// ============================================================
// scan1: per-1024-block scan of (deg + 1 self-loop per node)
// ============================================================
__global__ __launch_bounds__(256) void scan1_k(
    const int* __restrict__ deg, int* __restrict__ partial,
    int* __restrict__ bsum, int n)
{
    __shared__ int lds[256];
    int t = threadIdx.x;
    int base = blockIdx.x * 1024 + t * 4;
    int v0 = (base + 0 < n) ? deg[base + 0] + 1 : 0;
    int v1 = (base + 1 < n) ? deg[base + 1] + 1 : 0;
    int v2 = (base + 2 < n) ? deg[base + 2] + 1 : 0;
    int v3 = (base + 3 < n) ? deg[base + 3] + 1 : 0;
    int s = v0 + v1 + v2 + v3;
    lds[t] = s;
    __syncthreads();
    for (int o = 1; o < 256; o <<= 1) {
        int x = (t >= o) ? lds[t - o] : 0;
        __syncthreads();
        lds[t] += x;
        __syncthreads();
    }
    int excl = lds[t] - s;
    if (t == 255) bsum[blockIdx.x] = lds[255];
    if (base + 0 < n) partial[base + 0] = excl;
    if (base + 1 < n) partial[base + 1] = excl + v0;
    if (base + 2 < n) partial[base + 2] = excl + v0 + v1;
    if (base + 3 < n) partial[base + 3] = excl + v0 + v1 + v2;
}

// scan3: each block scans the (<=256) block sums itself, then emits rowptr.
__global__ __launch_bounds__(256) void scan3_k(
    const int* __restrict__ partial, const int* __restrict__ bsum,
    int* __restrict__ rowptr, int n, int EN, int nb)
{
    __shared__ int lds[256];
    int t = threadIdx.x;
    lds[t] = (t < nb) ? bsum[t] : 0;
    __syncthreads();
    for (int o = 1; o < 256; o <<= 1) {
        int x = (t >= o) ? lds[t - o] : 0;
        __syncthreads();
        lds[t] += x;
        __syncthreads();
    }
    int i = blockIdx.x * 256 + t;
    if (i == 0) rowptr[n] = EN;
    if (i >= n) return;
    int b = i >> 10;
    int pre = (b == 0) ? 0 : lds[b - 1];
    rowptr[i] = partial[i] + pre;
}

// atomic-free scatter. Real edges: slot rowptr[d]+rank[e].
// Self-loops: LAST slot of the segment, rowptr[d+1]-1.
__global__ __launch_bounds__(256) void fill_k(
    const int* __restrict__ ei, const int* __restrict__ rank,
    const int* __restrict__ rowptr, int* __restrict__ col, int E, int EN)
{
    int e = blockIdx.x * 256 + threadIdx.x;
    if (e >= EN) return;
    if (e < E) {
        int d = ei[E + e];
        col[rowptr[d] + rank[e]] = ei[e];
    } else {
        int d = e - E;
        col[rowptr[d + 1] - 1] = d;
    }
}

// ============================================================
// h = act(X [+bias]) @ W ; asrc/adst fp32; H stored bf16x2.
// relu_bias=0: layer 1 (raw X). relu_bias=1: layer 2.
// LDS-tiled W (proven best shape: ~27 us).
// ============================================================
__global__ __launch_bounds__(256) void gemm_attn(
    const float* __restrict__ X, const float* __restrict__ W,
    const float* __restrict__ av_s, const float* __restrict__ av_d,
    const float* __restrict__ bias, int relu_bias,
    unsigned* __restrict__ Hu, float* __restrict__ Asrc, float* __restrict__ Adst,
    int n)
{
    __shared__ float Ws[64 * 64];
    __shared__ float as_s[64], ad_s[64], b_s[64];
    int t = threadIdx.x;
    for (int i = t; i < 64 * 64; i += 256) Ws[i] = W[i];
    if (t < 64) { as_s[t] = av_s[t]; ad_s[t] = av_d[t]; b_s[t] = bias[t]; }
    __syncthreads();

    int row = blockIdx.x * 256 + t;
    if (row >= n) return;

    const float* xp = X + (size_t)row * 64;
    float xr[64];
    #pragma unroll
    for (int k = 0; k < 64; k += 4) {
        float4 v = *reinterpret_cast<const float4*>(xp + k);
        if (relu_bias) {
            v.x = fmaxf(v.x + b_s[k],     0.f);
            v.y = fmaxf(v.y + b_s[k + 1], 0.f);
            v.z = fmaxf(v.z + b_s[k + 2], 0.f);
            v.w = fmaxf(v.w + b_s[k + 3], 0.f);
        }
        xr[k] = v.x; xr[k + 1] = v.y; xr[k + 2] = v.z; xr[k + 3] = v.w;
    }

    float ss = 0.f, sd = 0.f;
    unsigned* hp = Hu + (size_t)row * 32;
    #pragma unroll 1
    for (int j = 0; j < 64; j += 4) {
        float a0 = 0.f, a1 = 0.f, a2 = 0.f, a3 = 0.f;
        #pragma unroll
        for (int k = 0; k < 64; k++) {
            float4 w = *reinterpret_cast<const float4*>(&Ws[k * 64 + j]);
            a0 += xr[k] * w.x; a1 += xr[k] * w.y;
            a2 += xr[k] * w.z; a3 += xr[k] * w.w;
        }
        uint2 o;
        o.x = f2bf(a0) | (f2bf(a1) << 16);
        o.y = f2bf(a2) | (f2bf(a3) << 16);
        *reinterpret_cast<uint2*>(hp + (j >> 1)) = o;
        ss += a0 * as_s[j] + a1 * as_s[j + 1] + a2 * as_s[j + 2] + a3 * as_s[j + 3];
        sd += a0 * ad_s[j] + a1 * ad_s[j + 1] + a2 * ad_s[j + 2] + a3 * ad_s[j + 3];
    }
    Asrc[row] = ss;
    Adst[row] = sd;
}

// ============================================================
// pull aggregation, two nodes per wave; optional fused
// classifier epilogue (layer 2): out = log_softmax(relu(row+b)@Wc+bc)
// ============================================================
__global__ __launch_bounds__(256) void node_agg_k(
    const int* __restrict__ rowptr, const int* __restrict__ col,
    const float* __restrict__ Asrc, const float* __restrict__ Adst,
    const unsigned* __restrict__ Hu, float* __restrict__ agg, int n,
    const float* __restrict__ cls_b, const float* __restrict__ Wc,
    const float* __restrict__ bc, float* __restrict__ out, int do_cls)
{
    __shared__ float lds_a[4][64];
    __shared__ int   lds_s[4][64];
    int wi   = threadIdx.x >> 6;
    int lane = threadIdx.x & 63;
    int half = lane >> 5, hl = lane & 31;
    int w2 = (blockIdx.x * 4 + wi) * 2;
    if (w2 >= n) return;
    int w  = w2 + half;
    int wc = (w < n) ? w : (n - 1);

    int beg = rowptr[wc];
    int deg = rowptr[wc + 1] - beg;
    bool fast = (deg <= 32);

    // ---- phase A: per-half register softmax ----
    int s = 0; float l = -3.4e38f;
    if (fast && hl < deg) {
        s = col[beg + hl];
        float v = Asrc[s] + Adst[wc];
        l = v > 0.f ? v : NEG_SLOPE * v;
    }
    float m = l;
    #pragma unroll
    for (int o = 16; o; o >>= 1) m = fmaxf(m, __shfl_xor(m, o, 64));
    float ex = (fast && hl < deg) ? __expf(l - m) : 0.f;
    float den = ex;
    #pragma unroll
    for (int o = 16; o; o >>= 1) den += __shfl_xor(den, o, 64);
    float alpha = ex / (den + 1e-16f);   // 0 on invalid/padded lanes

    const uint2* Hu2 = (const uint2*)Hu;
    int q = lane >> 4, fl = lane & 15;

    for (int h = 0; h < 2; h++) {
        int wn = w2 + h;
        if (wn >= n) break;
        int dg = __shfl(deg, h * 32, 64);

        if (dg <= 32) {
            int degP = (dg + 15) & ~15;          // 16 or 32
            float ax = 0.f, ay = 0.f, az = 0.f, aw = 0.f;
            for (int j = 0; j < degP; j += 16) {
                #pragma unroll
                for (int i = 0; i < 4; i++) {
                    int e   = j + 4 * i + q;
                    int idx = h * 32 + e;
                    int   se = __shfl(s,     idx, 64);
                    float pe = __shfl(alpha, idx, 64);
                    uint2 hv = Hu2[(size_t)se * 16 + fl];
                    ax += pe * __uint_as_float(hv.x << 16);
                    ay += pe * __uint_as_float(hv.x & 0xffff0000u);
                    az += pe * __uint_as_float(hv.y << 16);
                    aw += pe * __uint_as_float(hv.y & 0xffff0000u);
                }
            }
            ax += __shfl_xor(ax, 16, 64); ax += __shfl_xor(ax, 32, 64);
            ay += __shfl_xor(ay, 16, 64); ay += __shfl_xor(ay, 32, 64);
            az += __shfl_xor(az, 16, 64); az += __shfl_xor(az, 32, 64);
            aw += __shfl_xor(aw, 16, 64); aw += __shfl_xor(aw, 32, 64);
            if (do_cls) {
                float4 bb = *reinterpret_cast<const float4*>(cls_b + 4 * fl);
                float h0 = fmaxf(ax + bb.x, 0.f);
                float h1 = fmaxf(ay + bb.y, 0.f);
                float h2 = fmaxf(az + bb.z, 0.f);
                float h3 = fmaxf(aw + bb.w, 0.f);
                float4 wA = *reinterpret_cast<const float4*>(Wc + 8 * fl);
                float4 wB = *reinterpret_cast<const float4*>(Wc + 8 * fl + 4);
                float z0 = h0 * wA.x + h1 * wA.z + h2 * wB.x + h3 * wB.z;
                float z1 = h0 * wA.y + h1 * wA.w + h2 * wB.y + h3 * wB.w;
                #pragma unroll
                for (int o = 1; o < 16; o <<= 1) {
                    z0 += __shfl_xor(z0, o, 64);
                    z1 += __shfl_xor(z1, o, 64);
                }
                if (lane == 0) {
                    z0 += bc[0]; z1 += bc[1];
                    float mm = fmaxf(z0, z1);
                    float lse = mm + logf(__expf(z0 - mm) + __expf(z1 - mm));
                    out[(size_t)wn * 2]     = z0 - lse;
                    out[(size_t)wn * 2 + 1] = z1 - lse;
                }
            } else if (lane < 16) {
                float4 o; o.x = ax; o.y = ay; o.z = az; o.w = aw;
                *reinterpret_cast<float4*>(agg + (size_t)wn * 64 + 4 * fl) = o;
            }
        } else {
            // ---- generic fallback (deg > 32): full wave, lane = feature ----
            int begN = __shfl(beg, h * 32, 64);
            int endN = begN + dg;
            float adstN = Adst[wn];
            float mm = -3.4e38f;
            for (int i = begN + lane; i < endN; i += 64) {
                float v = Asrc[col[i]] + adstN;
                v = v > 0.f ? v : NEG_SLOPE * v;
                mm = fmaxf(mm, v);
            }
            #pragma unroll
            for (int o = 32; o; o >>= 1) mm = fmaxf(mm, __shfl_xor(mm, o, 64));
            float dd = 0.f;
            for (int i = begN + lane; i < endN; i += 64) {
                float v = Asrc[col[i]] + adstN;
                v = v > 0.f ? v : NEG_SLOPE * v;
                dd += __expf(v - mm);
            }
            #pragma unroll
            for (int o = 32; o; o >>= 1) dd += __shfl_xor(dd, o, 64);
            float inv = 1.f / (dd + 1e-16f);

            const unsigned short* Hs = (const unsigned short*)Hu;
            float acc = 0.f;
            for (int cbeg = begN; cbeg < endN; cbeg += 64) {
                int cnt = min(64, endN - cbeg);
                if (lane < cnt) {
                    int ss2 = col[cbeg + lane];
                    float v = Asrc[ss2] + adstN;
                    v = v > 0.f ? v : NEG_SLOPE * v;
                    lds_a[wi][lane] = __expf(v - mm) * inv;
                    lds_s[wi][lane] = ss2;
                }
                for (int j2 = 0; j2 < cnt; j2++) {
                    unsigned hv = (unsigned)Hs[(size_t)lds_s[wi][j2] * 64 + lane];
                    acc += lds_a[wi][j2] * __uint_as_float(hv << 16);
                }
            }
            if (do_cls) {
                float hh = fmaxf(acc + cls_b[lane], 0.f);
                float z0 = hh * Wc[2 * lane];
                float z1 = hh * Wc[2 * lane + 1];
                #pragma unroll
                for (int o = 1; o < 64; o <<= 1) {
                    z0 += __shfl_xor(z0, o, 64);
                    z1 += __shfl_xor(z1, o, 64);
                }
                if (lane == 0) {
                    z0 += bc[0]; z1 += bc[1];
                    float mm2 = fmaxf(z0, z1);
                    float lse = mm2 + logf(__expf(z0 - mm2) + __expf(z1 - mm2));
                    out[(size_t)wn * 2]     = z0 - lse;
                    out[(size_t)wn * 2 + 1] = z1 - lse;
                }
            } else {
                agg[(size_t)wn * 64 + lane] = acc;
            }
        }
    }
}

extern "C" void kernel_launch(void* const* d_in, const int* in_sizes, int n_in,
                              void* d_out, int out_size, void* d_ws, size_t ws_size,
                              hipStream_t stream)
{
    const float* x   = (const float*)d_in[0];
    const int*   ei  = (const int*)d_in[1];
    const float* W1  = (const float*)d_in[2];
    const float* as1 = (const float*)d_in[3];
    const float* ad1 = (const float*)d_in[4];
    const float* b1  = (const float*)d_in[5];
    const float* W2  = (const float*)d_in[6];
    const float* as2 = (const float*)d_in[7];
    const float* ad2 = (const float*)d_in[8];
    const float* b2  = (const float*)d_in[9];
    const float* Wc  = (const float*)d_in[10];
    const float* bc  = (const float*)d_in[11];
    float* out = (float*)d_out;

    const int N  = in_sizes[0] / 64;   // 100000
    const int E  = in_sizes[1] / 2;    // 1200000
    const int EN = E + N;

    // workspace: h[N*64] (bf16 H in first N*32 uints) | agg[N*64] | asrc[N] |
    // adst[N] | deg[N] | partial[N] | rowptr[N+1] | bsum[1024] | col[EN]
    // rank[E] aliases agg (dead by first node_agg).
    float* h    = (float*)d_ws;
    float* agg  = h + (size_t)N * 64;
    float* asrc = agg + (size_t)N * 64;
    float* adst = asrc + N;
    int* deg     = (int*)(adst + N);
    int* partial = deg + N;
    int* rowptr  = partial + N;
    int* bsum    = rowptr + (N + 1);
    int* col     = bsum + 1024;
    int* rank    = (int*)agg;
    unsigned* Hu = (unsigned*)h;

    const int gN  = (N + 255) / 256;
    const int gE  = (E + 255) / 256;     // real edges only (count)
    const int gEN = (EN + 255) / 256;    // all slots (fill)
    const int gSc = (N + 1023) / 1024;   // <= 256 (required by scan3)
    const int gW  = (N + 7) / 8;

    // ---------------- CSR build (atomics on real edges only) ----------------
    hipMemsetAsync(deg, 0, (size_t)N * sizeof(int), stream);
    count_rank_k<<<gE, 256, 0, stream>>>(ei, deg, rank, E);
    scan1_k<<<gSc, 256, 0, stream>>>(deg, partial, bsum, N);
    scan3_k<<<gN, 256, 0, stream>>>(partial, bsum, rowptr, N, EN, gSc);
    fill_k<<<gEN, 256, 0, stream>>>(ei, rank, rowptr, col, E, EN);

    // ---------------- layer 1 ----------------
    gemm_attn<<<gN, 256, 0, stream>>>(x, W1, as1, ad1, b1, 0, Hu, asrc, adst, N);
    node_agg_k<<<gW, 256, 0, stream>>>(rowptr, col, asrc, adst, Hu, agg, N,
                                       nullptr, nullptr, nullptr, nullptr, 0);

    // ---------------- layer 2 (bias+relu fused into GEMM load) ----------------
    gemm_attn<<<gN, 256, 0, stream>>>(agg, W2, as2, ad2, b1, 1, Hu, asrc, adst, N);

    // ---------------- layer 2 aggregation + classifier epilogue ----------------
    node_agg_k<<<gW, 256, 0, stream>>>(rowptr, col, asrc, adst, Hu, nullptr, N,
                                       b2, Wc, bc, out, 1);
}

// Round 9
// 306.875 us; speedup vs baseline: 1.0075x; 1.0075x over previous
//
#include <hip/hip_runtime.h>
#include <math.h>

#define NEG_SLOPE 0.2f

// fp32 -> bf16 round-to-nearest-even
__device__ __forceinline__ unsigned f2bf(float f) {
    unsigned u = __float_as_uint(f);
    return (u + 0x7fffu + ((u >> 16) & 1u)) >> 16;
}

// ============================================================
// count_rank over REAL edges only (self-loops take the last
// slot of each segment deterministically — no atomic needed).
// Standalone: at its atomic write-through floor (~42 MB @ ~0.9 TB/s).
// ============================================================
__global__ __launch_bounds__(256) void count_rank_k(
    const int* __restrict__ ei, int* __restrict__ deg, int* __restrict__ rank,
    int E)
{
    int e = blockIdx.x * 256 + threadIdx.x;
    if (e >= E) return;
    int d = ei[E + e];
    rank[e] = atomicAdd(&deg[d], 1);
}

// ============================================================
// scan1: per-1024-block scan of (deg + 1 self-loop per node)
// ============================================================
__global__ __launch_bounds__(256) void scan1_k(
    const int* __restrict__ deg, int* __restrict__ partial,
    int* __restrict__ bsum, int n)
{
    __shared__ int lds[256];
    int t = threadIdx.x;
    int base = blockIdx.x * 1024 + t * 4;
    int v0 = (base + 0 < n) ? deg[base + 0] + 1 : 0;
    int v1 = (base + 1 < n) ? deg[base + 1] + 1 : 0;
    int v2 = (base + 2 < n) ? deg[base + 2] + 1 : 0;
    int v3 = (base + 3 < n) ? deg[base + 3] + 1 : 0;
    int s = v0 + v1 + v2 + v3;
    lds[t] = s;
    __syncthreads();
    for (int o = 1; o < 256; o <<= 1) {
        int x = (t >= o) ? lds[t - o] : 0;
        __syncthreads();
        lds[t] += x;
        __syncthreads();
    }
    int excl = lds[t] - s;
    if (t == 255) bsum[blockIdx.x] = lds[255];
    if (base + 0 < n) partial[base + 0] = excl;
    if (base + 1 < n) partial[base + 1] = excl + v0;
    if (base + 2 < n) partial[base + 2] = excl + v0 + v1;
    if (base + 3 < n) partial[base + 3] = excl + v0 + v1 + v2;
}

// scan3: each block scans the (<=256) block sums itself, then emits rowptr.
__global__ __launch_bounds__(256) void scan3_k(
    const int* __restrict__ partial, const int* __restrict__ bsum,
    int* __restrict__ rowptr, int n, int EN, int nb)
{
    __shared__ int lds[256];
    int t = threadIdx.x;
    lds[t] = (t < nb) ? bsum[t] : 0;
    __syncthreads();
    for (int o = 1; o < 256; o <<= 1) {
        int x = (t >= o) ? lds[t - o] : 0;
        __syncthreads();
        lds[t] += x;
        __syncthreads();
    }
    int i = blockIdx.x * 256 + t;
    if (i == 0) rowptr[n] = EN;
    if (i >= n) return;
    int b = i >> 10;
    int pre = (b == 0) ? 0 : lds[b - 1];
    rowptr[i] = partial[i] + pre;
}

// ============================================================
// FUSED: fill (blocks [0,fillBlocks)) + layer-1 GEMM (rest).
// fill is a latency/scatter kernel (~0.5% VALU); gemm1 is
// VALU-bound and data-independent of fill -> complementary.
// fill blocks dispatched FIRST (longer pole).
// ============================================================
__global__ __launch_bounds__(256) void fill_gemm1_k(
    const int* __restrict__ ei, const int* __restrict__ rank,
    const int* __restrict__ rowptr, int* __restrict__ col, int E, int EN,
    int fillBlocks,
    const float* __restrict__ X, const float* __restrict__ W,
    const float* __restrict__ av_s, const float* __restrict__ av_d,
    unsigned* __restrict__ Hu, float* __restrict__ Asrc, float* __restrict__ Adst,
    int n)
{
    __shared__ float Ws[64 * 64];
    __shared__ float as_s[64], ad_s[64];
    int t = threadIdx.x;

    if (blockIdx.x < fillBlocks) {
        // ---- fill path: atomic-free scatter ----
        int e = blockIdx.x * 256 + t;
        if (e >= EN) return;
        if (e < E) {
            int d = ei[E + e];
            col[rowptr[d] + rank[e]] = ei[e];
        } else {
            int d = e - E;
            col[rowptr[d + 1] - 1] = d;   // self-loop -> last slot
        }
        return;
    }

    // ---- GEMM path (layer 1, no activation) ----
    for (int i = t; i < 64 * 64; i += 256) Ws[i] = W[i];
    if (t < 64) { as_s[t] = av_s[t]; ad_s[t] = av_d[t]; }
    __syncthreads();

    int row = (blockIdx.x - fillBlocks) * 256 + t;
    if (row >= n) return;

    const float* xp = X + (size_t)row * 64;
    float xr[64];
    #pragma unroll
    for (int k = 0; k < 64; k += 4) {
        float4 v = *reinterpret_cast<const float4*>(xp + k);
        xr[k] = v.x; xr[k + 1] = v.y; xr[k + 2] = v.z; xr[k + 3] = v.w;
    }

    float ss = 0.f, sd = 0.f;
    unsigned* hp = Hu + (size_t)row * 32;
    #pragma unroll 1
    for (int j = 0; j < 64; j += 4) {
        float a0 = 0.f, a1 = 0.f, a2 = 0.f, a3 = 0.f;
        #pragma unroll
        for (int k = 0; k < 64; k++) {
            float4 w = *reinterpret_cast<const float4*>(&Ws[k * 64 + j]);
            a0 += xr[k] * w.x; a1 += xr[k] * w.y;
            a2 += xr[k] * w.z; a3 += xr[k] * w.w;
        }
        uint2 o;
        o.x = f2bf(a0) | (f2bf(a1) << 16);
        o.y = f2bf(a2) | (f2bf(a3) << 16);
        *reinterpret_cast<uint2*>(hp + (j >> 1)) = o;
        ss += a0 * as_s[j] + a1 * as_s[j + 1] + a2 * as_s[j + 2] + a3 * as_s[j + 3];
        sd += a0 * ad_s[j] + a1 * ad_s[j + 1] + a2 * ad_s[j + 2] + a3 * ad_s[j + 3];
    }
    Asrc[row] = ss;
    Adst[row] = sd;
}

// ============================================================
// layer-2 GEMM: h = relu(X + bias) @ W ; H bf16; LDS-tiled W
// ============================================================
__global__ __launch_bounds__(256) void gemm_attn(
    const float* __restrict__ X, const float* __restrict__ W,
    const float* __restrict__ av_s, const float* __restrict__ av_d,
    const float* __restrict__ bias,
    unsigned* __restrict__ Hu, float* __restrict__ Asrc, float* __restrict__ Adst,
    int n)
{
    __shared__ float Ws[64 * 64];
    __shared__ float as_s[64], ad_s[64], b_s[64];
    int t = threadIdx.x;
    for (int i = t; i < 64 * 64; i += 256) Ws[i] = W[i];
    if (t < 64) { as_s[t] = av_s[t]; ad_s[t] = av_d[t]; b_s[t] = bias[t]; }
    __syncthreads();

    int row = blockIdx.x * 256 + t;
    if (row >= n) return;

    const float* xp = X + (size_t)row * 64;
    float xr[64];
    #pragma unroll
    for (int k = 0; k < 64; k += 4) {
        float4 v = *reinterpret_cast<const float4*>(xp + k);
        v.x = fmaxf(v.x + b_s[k],     0.f);
        v.y = fmaxf(v.y + b_s[k + 1], 0.f);
        v.z = fmaxf(v.z + b_s[k + 2], 0.f);
        v.w = fmaxf(v.w + b_s[k + 3], 0.f);
        xr[k] = v.x; xr[k + 1] = v.y; xr[k + 2] = v.z; xr[k + 3] = v.w;
    }

    float ss = 0.f, sd = 0.f;
    unsigned* hp = Hu + (size_t)row * 32;
    #pragma unroll 1
    for (int j = 0; j < 64; j += 4) {
        float a0 = 0.f, a1 = 0.f, a2 = 0.f, a3 = 0.f;
        #pragma unroll
        for (int k = 0; k < 64; k++) {
            float4 w = *reinterpret_cast<const float4*>(&Ws[k * 64 + j]);
            a0 += xr[k] * w.x; a1 += xr[k] * w.y;
            a2 += xr[k] * w.z; a3 += xr[k] * w.w;
        }
        uint2 o;
        o.x = f2bf(a0) | (f2bf(a1) << 16);
        o.y = f2bf(a2) | (f2bf(a3) << 16);
        *reinterpret_cast<uint2*>(hp + (j >> 1)) = o;
        ss += a0 * as_s[j] + a1 * as_s[j + 1] + a2 * as_s[j + 2] + a3 * as_s[j + 3];
        sd += a0 * ad_s[j] + a1 * ad_s[j + 1] + a2 * ad_s[j + 2] + a3 * ad_s[j + 3];
    }
    Asrc[row] = ss;
    Adst[row] = sd;
}

// ============================================================
// pull aggregation, two nodes per wave. Phase B INTERLEAVES the
// two nodes' gathers (8 loads in flight, one shared reduction).
// Optional fused classifier epilogue (layer 2).
// ============================================================
__global__ __launch_bounds__(256) void node_agg_k(
    const int* __restrict__ rowptr, const int* __restrict__ col,
    const float* __restrict__ Asrc, const float* __restrict__ Adst,
    const unsigned* __restrict__ Hu, float* __restrict__ agg, int n,
    const float* __restrict__ cls_b, const float* __restrict__ Wc,
    const float* __restrict__ bc, float* __restrict__ out, int do_cls)
{
    __shared__ float lds_a[4][64];
    __shared__ int   lds_s[4][64];
    int wi   = threadIdx.x >> 6;
    int lane = threadIdx.x & 63;
    int half = lane >> 5, hl = lane & 31;
    int w2 = (blockIdx.x * 4 + wi) * 2;
    if (w2 >= n) return;
    int w  = w2 + half;
    int wc = (w < n) ? w : (n - 1);

    int beg = rowptr[wc];
    int deg = rowptr[wc + 1] - beg;
    bool fast = (deg <= 32);

    // ---- phase A: per-half register softmax ----
    int s = 0; float l = -3.4e38f;
    if (fast && hl < deg) {
        s = col[beg + hl];
        float v = Asrc[s] + Adst[wc];
        l = v > 0.f ? v : NEG_SLOPE * v;
    }
    float m = l;
    #pragma unroll
    for (int o = 16; o; o >>= 1) m = fmaxf(m, __shfl_xor(m, o, 64));
    float ex = (fast && hl < deg) ? __expf(l - m) : 0.f;
    float den = ex;
    #pragma unroll
    for (int o = 16; o; o >>= 1) den += __shfl_xor(den, o, 64);
    float alpha = ex / (den + 1e-16f);   // 0 on invalid/padded lanes

    const uint2* Hu2 = (const uint2*)Hu;
    int q = lane >> 4, fl = lane & 15;

    int dgA = __shfl(deg, 0, 64);
    int dgB = __shfl(deg, 32, 64);
    bool hasB = (w2 + 1 < n);

    if (dgA <= 32 && (!hasB || dgB <= 32)) {
        // ---- interleaved phase B: both nodes in one stream ----
        int dmax = (hasB && dgB > dgA) ? dgB : dgA;
        int degP = (dmax + 15) & ~15;            // 16 or 32
        float axA = 0.f, ayA = 0.f, azA = 0.f, awA = 0.f;
        float axB = 0.f, ayB = 0.f, azB = 0.f, awB = 0.f;
        for (int j = 0; j < degP; j += 16) {
            #pragma unroll
            for (int i = 0; i < 4; i++) {
                int e = j + 4 * i + q;           // e in [0,32)
                int   sA = __shfl(s,     e,      64);
                float pA = __shfl(alpha, e,      64);
                int   sB = __shfl(s,     32 + e, 64);
                float pB = __shfl(alpha, 32 + e, 64);
                uint2 hA = Hu2[(size_t)sA * 16 + fl];
                uint2 hB = Hu2[(size_t)sB * 16 + fl];
                axA += pA * __uint_as_float(hA.x << 16);
                ayA += pA * __uint_as_float(hA.x & 0xffff0000u);
                azA += pA * __uint_as_float(hA.y << 16);
                awA += pA * __uint_as_float(hA.y & 0xffff0000u);
                axB += pB * __uint_as_float(hB.x << 16);
                ayB += pB * __uint_as_float(hB.x & 0xffff0000u);
                azB += pB * __uint_as_float(hB.y << 16);
                awB += pB * __uint_as_float(hB.y & 0xffff0000u);
            }
        }
        // cross-quarter reduction (all lanes end with both nodes' totals)
        axA += __shfl_xor(axA, 16, 64); axA += __shfl_xor(axA, 32, 64);
        ayA += __shfl_xor(ayA, 16, 64); ayA += __shfl_xor(ayA, 32, 64);
        azA += __shfl_xor(azA, 16, 64); azA += __shfl_xor(azA, 32, 64);
        awA += __shfl_xor(awA, 16, 64); awA += __shfl_xor(awA, 32, 64);
        axB += __shfl_xor(axB, 16, 64); axB += __shfl_xor(axB, 32, 64);
        ayB += __shfl_xor(ayB, 16, 64); ayB += __shfl_xor(ayB, 32, 64);
        azB += __shfl_xor(azB, 16, 64); azB += __shfl_xor(azB, 32, 64);
        awB += __shfl_xor(awB, 16, 64); awB += __shfl_xor(awB, 32, 64);

        if (do_cls) {
            bool isB = (lane & 16) != 0;         // groups 1,3 -> node B
            float cx = isB ? axB : axA;
            float cy = isB ? ayB : ayA;
            float cz = isB ? azB : azA;
            float cw = isB ? awB : awA;
            float4 bb = *reinterpret_cast<const float4*>(cls_b + 4 * fl);
            float h0 = fmaxf(cx + bb.x, 0.f);
            float h1 = fmaxf(cy + bb.y, 0.f);
            float h2 = fmaxf(cz + bb.z, 0.f);
            float h3 = fmaxf(cw + bb.w, 0.f);
            float4 wA_ = *reinterpret_cast<const float4*>(Wc + 8 * fl);
            float4 wB_ = *reinterpret_cast<const float4*>(Wc + 8 * fl + 4);
            float z0 = h0 * wA_.x + h1 * wA_.z + h2 * wB_.x + h3 * wB_.z;
            float z1 = h0 * wA_.y + h1 * wA_.w + h2 * wB_.y + h3 * wB_.w;
            #pragma unroll
            for (int o = 1; o < 16; o <<= 1) {
                z0 += __shfl_xor(z0, o, 64);
                z1 += __shfl_xor(z1, o, 64);
            }
            if (lane == 0 || (lane == 16 && hasB)) {
                int wn = w2 + (lane >> 4);
                float za = z0 + bc[0], zb = z1 + bc[1];
                float mm = fmaxf(za, zb);
                float lse = mm + logf(__expf(za - mm) + __expf(zb - mm));
                out[(size_t)wn * 2]     = za - lse;
                out[(size_t)wn * 2 + 1] = zb - lse;
            }
        } else {
            if (lane < 16) {
                float4 o; o.x = axA; o.y = ayA; o.z = azA; o.w = awA;
                *reinterpret_cast<float4*>(agg + (size_t)w2 * 64 + 4 * fl) = o;
            } else if (lane < 32 && hasB) {
                float4 o; o.x = axB; o.y = ayB; o.z = azB; o.w = awB;
                *reinterpret_cast<float4*>(agg + (size_t)(w2 + 1) * 64 + 4 * fl) = o;
            }
        }
        return;
    }

    // ---- fallback: sequential per node (rare: deg > 32) ----
    for (int h = 0; h < 2; h++) {
        int wn = w2 + h;
        if (wn >= n) break;
        int dg = __shfl(deg, h * 32, 64);

        if (dg <= 32) {
            int degP = (dg + 15) & ~15;
            float ax = 0.f, ay = 0.f, az = 0.f, aw = 0.f;
            for (int j = 0; j < degP; j += 16) {
                #pragma unroll
                for (int i = 0; i < 4; i++) {
                    int e   = j + 4 * i + q;
                    int idx = h * 32 + e;
                    int   se = __shfl(s,     idx, 64);
                    float pe = __shfl(alpha, idx, 64);
                    uint2 hv = Hu2[(size_t)se * 16 + fl];
                    ax += pe * __uint_as_float(hv.x << 16);
                    ay += pe * __uint_as_float(hv.x & 0xffff0000u);
                    az += pe * __uint_as_float(hv.y << 16);
                    aw += pe * __uint_as_float(hv.y & 0xffff0000u);
                }
            }
            ax += __shfl_xor(ax, 16, 64); ax += __shfl_xor(ax, 32, 64);
            ay += __shfl_xor(ay, 16, 64); ay += __shfl_xor(ay, 32, 64);
            az += __shfl_xor(az, 16, 64); az += __shfl_xor(az, 32, 64);
            aw += __shfl_xor(aw, 16, 64); aw += __shfl_xor(aw, 32, 64);
            if (do_cls) {
                float4 bb = *reinterpret_cast<const float4*>(cls_b + 4 * fl);
                float h0 = fmaxf(ax + bb.x, 0.f);
                float h1 = fmaxf(ay + bb.y, 0.f);
                float h2 = fmaxf(az + bb.z, 0.f);
                float h3 = fmaxf(aw + bb.w, 0.f);
                float4 wA_ = *reinterpret_cast<const float4*>(Wc + 8 * fl);
                float4 wB_ = *reinterpret_cast<const float4*>(Wc + 8 * fl + 4);
                float z0 = h0 * wA_.x + h1 * wA_.z + h2 * wB_.x + h3 * wB_.z;
                float z1 = h0 * wA_.y + h1 * wA_.w + h2 * wB_.y + h3 * wB_.w;
                #pragma unroll
                for (int o = 1; o < 16; o <<= 1) {
                    z0 += __shfl_xor(z0, o, 64);
                    z1 += __shfl_xor(z1, o, 64);
                }
                if (lane == 0) {
                    z0 += bc[0]; z1 += bc[1];
                    float mm = fmaxf(z0, z1);
                    float lse = mm + logf(__expf(z0 - mm) + __expf(z1 - mm));
                    out[(size_t)wn * 2]     = z0 - lse;
                    out[(size_t)wn * 2 + 1] = z1 - lse;
                }
            } else if (lane < 16) {
                float4 o; o.x = ax; o.y = ay; o.z = az; o.w = aw;
                *reinterpret_cast<float4*>(agg + (size_t)wn * 64 + 4 * fl) = o;
            }
        } else {
            // generic (deg > 32): full wave, lane = feature
            int begN = __shfl(beg, h * 32, 64);
            int endN = begN + dg;
            float adstN = Adst[wn];
            float mm = -3.4e38f;
            for (int i = begN + lane; i < endN; i += 64) {
                float v = Asrc[col[i]] + adstN;
                v = v > 0.f ? v : NEG_SLOPE * v;
                mm = fmaxf(mm, v);
            }
            #pragma unroll
            for (int o = 32; o; o >>= 1) mm = fmaxf(mm, __shfl_xor(mm, o, 64));
            float dd = 0.f;
            for (int i = begN + lane; i < endN; i += 64) {
                float v = Asrc[col[i]] + adstN;
                v = v > 0.f ? v : NEG_SLOPE * v;
                dd += __expf(v - mm);
            }
            #pragma unroll
            for (int o = 32; o; o >>= 1) dd += __shfl_xor(dd, o, 64);
            float inv = 1.f / (dd + 1e-16f);

            const unsigned short* Hs = (const unsigned short*)Hu;
            float acc = 0.f;
            for (int cbeg = begN; cbeg < endN; cbeg += 64) {
                int cnt = min(64, endN - cbeg);
                if (lane < cnt) {
                    int ss2 = col[cbeg + lane];
                    float v = Asrc[ss2] + adstN;
                    v = v > 0.f ? v : NEG_SLOPE * v;
                    lds_a[wi][lane] = __expf(v - mm) * inv;
                    lds_s[wi][lane] = ss2;
                }
                for (int j2 = 0; j2 < cnt; j2++) {
                    unsigned hv = (unsigned)Hs[(size_t)lds_s[wi][j2] * 64 + lane];
                    acc += lds_a[wi][j2] * __uint_as_float(hv << 16);
                }
            }
            if (do_cls) {
                float hh = fmaxf(acc + cls_b[lane], 0.f);
                float z0 = hh * Wc[2 * lane];
                float z1 = hh * Wc[2 * lane + 1];
                #pragma unroll
                for (int o = 1; o < 64; o <<= 1) {
                    z0 += __shfl_xor(z0, o, 64);
                    z1 += __shfl_xor(z1, o, 64);
                }
                if (lane == 0) {
                    z0 += bc[0]; z1 += bc[1];
                    float mm2 = fmaxf(z0, z1);
                    float lse = mm2 + logf(__expf(z0 - mm2) + __expf(z1 - mm2));
                    out[(size_t)wn * 2]     = z0 - lse;
                    out[(size_t)wn * 2 + 1] = z1 - lse;
                }
            } else {
                agg[(size_t)wn * 64 + lane] = acc;
            }
        }
    }
}

extern "C" void kernel_launch(void* const* d_in, const int* in_sizes, int n_in,
                              void* d_out, int out_size, void* d_ws, size_t ws_size,
                              hipStream_t stream)
{
    const float* x   = (const float*)d_in[0];
    const int*   ei  = (const int*)d_in[1];
    const float* W1  = (const float*)d_in[2];
    const float* as1 = (const float*)d_in[3];
    const float* ad1 = (const float*)d_in[4];
    const float* b1  = (const float*)d_in[5];
    const float* W2  = (const float*)d_in[6];
    const float* as2 = (const float*)d_in[7];
    const float* ad2 = (const float*)d_in[8];
    const float* b2  = (const float*)d_in[9];
    const float* Wc  = (const float*)d_in[10];
    const float* bc  = (const float*)d_in[11];
    float* out = (float*)d_out;

    const int N  = in_sizes[0] / 64;   // 100000
    const int E  = in_sizes[1] / 2;    // 1200000
    const int EN = E + N;

    // workspace: h[N*64] (bf16 H in first N*32 uints) | agg[N*64] | asrc[N] |
    // adst[N] | deg[N] | partial[N] | rowptr[N+1] | bsum[1024] | col[EN]
    // rank[E] aliases agg (dead by first node_agg).
    float* h    = (float*)d_ws;
    float* agg  = h + (size_t)N * 64;
    float* asrc = agg + (size_t)N * 64;
    float* adst = asrc + N;
    int* deg     = (int*)(adst + N);
    int* partial = deg + N;
    int* rowptr  = partial + N;
    int* bsum    = rowptr + (N + 1);
    int* col     = bsum + 1024;
    int* rank    = (int*)agg;
    unsigned* Hu = (unsigned*)h;

    const int gN  = (N + 255) / 256;
    const int gE  = (E + 255) / 256;     // real edges only (count)
    const int gEN = (EN + 255) / 256;    // all slots (fill)
    const int gSc = (N + 1023) / 1024;   // <= 256 (required by scan3)
    const int gW  = (N + 7) / 8;

    // ---------------- CSR build ----------------
    hipMemsetAsync(deg, 0, (size_t)N * sizeof(int), stream);
    count_rank_k<<<gE, 256, 0, stream>>>(ei, deg, rank, E);
    scan1_k<<<gSc, 256, 0, stream>>>(deg, partial, bsum, N);
    scan3_k<<<gN, 256, 0, stream>>>(partial, bsum, rowptr, N, EN, gSc);

    // ---------------- fill + layer-1 GEMM (fused, fill first) ----------------
    fill_gemm1_k<<<gEN + gN, 256, 0, stream>>>(
        ei, rank, rowptr, col, E, EN, gEN,
        x, W1, as1, ad1, Hu, asrc, adst, N);

    // ---------------- layer 1 aggregation ----------------
    node_agg_k<<<gW, 256, 0, stream>>>(rowptr, col, asrc, adst, Hu, agg, N,
                                       nullptr, nullptr, nullptr, nullptr, 0);

    // ---------------- layer 2 (bias+relu fused into GEMM load) ----------------
    gemm_attn<<<gN, 256, 0, stream>>>(agg, W2, as2, ad2, b1, Hu, asrc, adst, N);

    // ---------------- layer 2 aggregation + classifier epilogue ----------------
    node_agg_k<<<gW, 256, 0, stream>>>(rowptr, col, asrc, adst, Hu, nullptr, N,
                                       b2, Wc, bc, out, 1);
}